// Round 8
// baseline (115.216 us; speedup 1.0000x reference)
//
#include <hip/hip_runtime.h>
#include <hip/hip_fp16.h>

#define H 64
#define R 5

typedef float    v2f __attribute__((ext_vector_type(2)));
typedef _Float16 v2h __attribute__((ext_vector_type(2)));

static __device__ __forceinline__ v2f fma2(v2f a, v2f b, v2f c) {
#if __has_builtin(__builtin_elementwise_fma)
    return __builtin_elementwise_fma(a, b, c);
#else
    return a * b + c;
#endif
}

// fp16 2-way dot with fp32 accumulate: v_dot2_f32_f16
static __device__ __forceinline__ float dot2(v2h a, v2h b, float c) {
#if __has_builtin(__builtin_amdgcn_fdot2)
    return __builtin_amdgcn_fdot2(a, b, c, false);
#else
    return (float)a.x * (float)b.x + (float)a.y * (float)b.y + c;
#endif
}

static __device__ __forceinline__ v2h bch(unsigned u) {
    return __builtin_bit_cast(v2h, u);
}

// pack two fp32 -> fp16 pair (RNE) in one uint
static __device__ __forceinline__ unsigned h2pair(float a, float b) {
    __half2 h = __floats2half2_rn(a, b);
    return *(const unsigned*)&h;
}

// Streaming prep: z_user, z_movie AND rel_emb -> fp16 in workspace.
__global__ __launch_bounds__(256) void convert_f16_kernel(
    const float4* __restrict__ zu4, const float4* __restrict__ zm4,
    const float4* __restrict__ rel4,
    uint4* __restrict__ wu, uint4* __restrict__ wm, uint4* __restrict__ wr,
    int n_u_chunks, int n_m_chunks, int n_r_chunks)
{
    int t = blockIdx.x * blockDim.x + threadIdx.x;
    const float4* src;
    uint4* dst;
    int c;
    if (t < n_u_chunks)                   { src = zu4;  dst = wu; c = t; }
    else if (t < n_u_chunks + n_m_chunks) { src = zm4;  dst = wm; c = t - n_u_chunks; }
    else if (t < n_u_chunks + n_m_chunks + n_r_chunks)
                                          { src = rel4; dst = wr; c = t - n_u_chunks - n_m_chunks; }
    else return;
    float4 f0 = src[2 * c];
    float4 f1 = src[2 * c + 1];
    uint4 o;
    o.x = h2pair(f0.x, f0.y);
    o.y = h2pair(f0.z, f0.w);
    o.z = h2pair(f1.x, f1.y);
    o.w = h2pair(f1.z, f1.w);
    dst[c] = o;
}

// Main pass: quad handles 4 edges; straight-line named-scalar code only
// (arrays get demoted to LDS by AMDGPUPromoteAlloca — round 6 evidence:
// LDS_Block_Size=20480, 593k bank conflicts). 16 independent row loads
// back-to-back. Round-8 changes vs round 7:
//  * rel fragments loaded LAZILY inside each REDUCE scope (L1-resident,
//    ~50cy) instead of preloaded — removes ~40 VGPR from the peak window
//    (peak = rows 64 + products 16 + misc, not +rel 40).
//  * __launch_bounds__(256, 4): pin >=4 waves/SIMD (16 waves/CU) so each CU
//    holds >=256 outstanding row-lines against the ~700cy L2-miss latency.
// Lane l of a quad reads 16B chunk l and 4+l of each 128B row -> one
// contiguous 64B line per quad per load instr (minimal 4 line txns/edge).
// Lane l owns edge base+l for softmax (all 64 lanes active, coalesced store).
__global__ __launch_bounds__(256, 4) void edge_decoder_f16s_kernel(
    const uint4* __restrict__ wu,    // fp16 rows, 8 uint4 per row
    const uint4* __restrict__ wm,
    const uint4* __restrict__ wr,    // fp16 rel_emb, 8 uint4 per relation
    const int*   __restrict__ idx,
    float*       __restrict__ out,
    int E)
{
    int tid  = blockIdx.x * blockDim.x + threadIdx.x;
    int l    = tid & 3;
    int base = tid & ~3;
    if (base >= E) return;          // whole quad out of range

    int su_l = 0, sm_l = 0;
    if (tid < E) { su_l = idx[tid]; sm_l = idx[E + tid]; }

    int su0 = __shfl(su_l, 0, 4);
    int su1 = __shfl(su_l, 1, 4);
    int su2 = __shfl(su_l, 2, 4);
    int su3 = __shfl(su_l, 3, 4);
    int sm0 = __shfl(sm_l, 0, 4);
    int sm1 = __shfl(sm_l, 1, 4);
    int sm2 = __shfl(sm_l, 2, 4);
    int sm3 = __shfl(sm_l, 3, 4);

    // 16 independent row loads, issued back-to-back (the L2-miss traffic)
#define ROWS(j)                                          \
    uint4 a0_##j = wu[(size_t)su##j * 8 + l];            \
    uint4 a1_##j = wu[(size_t)su##j * 8 + 4 + l];        \
    uint4 b0_##j = wm[(size_t)sm##j * 8 + l];            \
    uint4 b1_##j = wm[(size_t)sm##j * 8 + 4 + l];
    ROWS(0) ROWS(1) ROWS(2) ROWS(3)
#undef ROWS

    // products: 8 v2h per edge (v_pk_mul_f16); frees the row regs
#define MAKE_P(j)                                        \
    v2h p##j##_0 = bch(a0_##j.x) * bch(b0_##j.x);        \
    v2h p##j##_1 = bch(a0_##j.y) * bch(b0_##j.y);        \
    v2h p##j##_2 = bch(a0_##j.z) * bch(b0_##j.z);        \
    v2h p##j##_3 = bch(a0_##j.w) * bch(b0_##j.w);        \
    v2h p##j##_4 = bch(a1_##j.x) * bch(b1_##j.x);        \
    v2h p##j##_5 = bch(a1_##j.y) * bch(b1_##j.y);        \
    v2h p##j##_6 = bch(a1_##j.z) * bch(b1_##j.z);        \
    v2h p##j##_7 = bch(a1_##j.w) * bch(b1_##j.w);
    MAKE_P(0) MAKE_P(1) MAKE_P(2) MAKE_P(3)
#undef MAKE_P

    bool c1 = (l & 1) != 0;
    bool c2 = (l & 2) != 0;

    // 8-term fp16 dot (fp32 accum) for edge j, relation r
#define SCORE(j, r)                                                   \
    dot2(p##j##_7, bch(w1_##r.w), dot2(p##j##_6, bch(w1_##r.z),       \
    dot2(p##j##_5, bch(w1_##r.y), dot2(p##j##_4, bch(w1_##r.x),       \
    dot2(p##j##_3, bch(w0_##r.w), dot2(p##j##_2, bch(w0_##r.z),       \
    dot2(p##j##_1, bch(w0_##r.y), dot2(p##j##_0, bch(w0_##r.x), 0.f))))))))

    float sc0, sc1, sc2, sc3, sc4;
    // per-r: load rel fragments (L1-resident), 4 partial scores, quad
    // butterfly, lane-mux; all temporaries die at the closing brace.
#define REDUCE(r, scr) {                                              \
        uint4 w0_##r = wr[r * 8 + l];                                 \
        uint4 w1_##r = wr[r * 8 + 4 + l];                             \
        float s0 = SCORE(0, r);                                       \
        float s1 = SCORE(1, r);                                       \
        float s2 = SCORE(2, r);                                       \
        float s3 = SCORE(3, r);                                       \
        s0 += __shfl_xor(s0, 1); s1 += __shfl_xor(s1, 1);             \
        s2 += __shfl_xor(s2, 1); s3 += __shfl_xor(s3, 1);             \
        s0 += __shfl_xor(s0, 2); s1 += __shfl_xor(s1, 2);             \
        s2 += __shfl_xor(s2, 2); s3 += __shfl_xor(s3, 2);             \
        scr = c2 ? (c1 ? s3 : s2) : (c1 ? s1 : s0);                   \
    }
    REDUCE(0, sc0) REDUCE(1, sc1) REDUCE(2, sc2) REDUCE(3, sc3) REDUCE(4, sc4)
#undef REDUCE
#undef SCORE

    float mx = fmaxf(fmaxf(fmaxf(sc0, sc1), fmaxf(sc2, sc3)), sc4);
    float e0 = __expf(sc0 - mx);
    float e1 = __expf(sc1 - mx);
    float e2 = __expf(sc2 - mx);
    float e3 = __expf(sc3 - mx);
    float e4 = __expf(sc4 - mx);
    float den = e0 + e1 + e2 + e3 + e4;
    float num = fmaf(4.f, e4, fmaf(3.f, e3, fmaf(2.f, e2, e1)));
    if (tid < E) out[tid] = num * __frcp_rn(den);
}

// ---- fp32 fallback (round-3 kernel) if ws is too small for fp16 tables ----
__global__ __launch_bounds__(256) void edge_decoder_f32_kernel(
    const float4* __restrict__ zu4, const float4* __restrict__ zm4,
    const float4* __restrict__ rel4, const int* __restrict__ idx,
    float* __restrict__ out, int E)
{
    int tid = blockIdx.x * blockDim.x + threadIdx.x;
    int l   = threadIdx.x & 3;
    int e   = tid >> 2;
    if (e >= E) return;
    int su = idx[e];
    int sm = idx[E + e];
    const float4* arow = zu4 + su * 16;
    const float4* brow = zm4 + sm * 16;
    v2f plo[4], phi[4];
#pragma unroll
    for (int i = 0; i < 4; ++i) {
        float4 av = arow[4 * i + l];
        float4 bv = brow[4 * i + l];
        v2f alo = {av.x, av.y}, ahi = {av.z, av.w};
        v2f blo = {bv.x, bv.y}, bhi = {bv.z, bv.w};
        plo[i] = alo * blo;
        phi[i] = ahi * bhi;
    }
    float s[R];
#pragma unroll
    for (int r = 0; r < R; ++r) {
        v2f acc = {0.f, 0.f};
#pragma unroll
        for (int i = 0; i < 4; ++i) {
            float4 w = rel4[r * 16 + 4 * i + l];
            acc = fma2(plo[i], (v2f){w.x, w.y}, acc);
            acc = fma2(phi[i], (v2f){w.z, w.w}, acc);
        }
        s[r] = acc.x + acc.y;
    }
#pragma unroll
    for (int r = 0; r < R; ++r) s[r] += __shfl_xor(s[r], 1);
#pragma unroll
    for (int r = 0; r < R; ++r) s[r] += __shfl_xor(s[r], 2);
    if (l == 0) {
        float mx = fmaxf(fmaxf(fmaxf(s[0], s[1]), fmaxf(s[2], s[3])), s[4]);
        float e0 = __expf(s[0] - mx);
        float e1 = __expf(s[1] - mx);
        float e2 = __expf(s[2] - mx);
        float e3 = __expf(s[3] - mx);
        float e4 = __expf(s[4] - mx);
        float den = e0 + e1 + e2 + e3 + e4;
        float num = fmaf(4.f, e4, fmaf(3.f, e3, fmaf(2.f, e2, e1)));
        out[e] = num * __frcp_rn(den);
    }
}

extern "C" void kernel_launch(void* const* d_in, const int* in_sizes, int n_in,
                              void* d_out, int out_size, void* d_ws, size_t ws_size,
                              hipStream_t stream) {
    const float4* zu4  = (const float4*)d_in[0];   // z_user   [NU,64]
    const float4* zm4  = (const float4*)d_in[1];   // z_movie  [NM,64]
    const float4* rel4 = (const float4*)d_in[2];   // rel_emb  [5,64]
    const int*    idx  = (const int*)d_in[3];      // edge_label_index [2,E]
    float* out = (float*)d_out;

    int E  = in_sizes[3] / 2;
    int nu = in_sizes[0] / H;   // user rows
    int nm = in_sizes[1] / H;   // movie rows

    size_t need = (size_t)(nu + nm + R) * H * 2;   // fp16 tables + rel
    int block = 256;

    if (ws_size >= need) {
        uint4* wu = (uint4*)d_ws;              // nu*8 uint4
        uint4* wm = wu + (size_t)nu * 8;       // nm*8 uint4
        uint4* wr = wm + (size_t)nm * 8;       // R*8 uint4

        int n_u_chunks = nu * (H / 8);
        int n_m_chunks = nm * (H / 8);
        int n_r_chunks = R * (H / 8);
        int conv_threads = n_u_chunks + n_m_chunks + n_r_chunks;
        int conv_grid = (conv_threads + block - 1) / block;
        convert_f16_kernel<<<conv_grid, block, 0, stream>>>(
            zu4, zm4, rel4, wu, wm, wr, n_u_chunks, n_m_chunks, n_r_chunks);

        long long threads = (long long)E;      // 1 lane per edge owned
        int grid = (int)((threads + block - 1) / block);
        edge_decoder_f16s_kernel<<<grid, block, 0, stream>>>(
            wu, wm, wr, idx, out, E);
    } else {
        long long threads = (long long)E * 4;
        int grid = (int)((threads + block - 1) / block);
        edge_decoder_f32_kernel<<<grid, block, 0, stream>>>(
            zu4, zm4, rel4, idx, out, E);
    }
}